// Round 1
// 828.379 us; speedup vs baseline: 1.1195x; 1.1195x over previous
//
#include <hip/hip_runtime.h>

// UAG-RNN 4-neighbor, two directional scans — round 4 restructure.
//
// Key change: the parallel half of the recurrence (W1*x + b1 + b2) is hoisted
// out of the serial scan into a separate memory-bound kernel ("prelin") that
// ALSO transposes into a scan-friendly layout A[b][q][p][o] (o innermost).
// The scan's per-step global load becomes one coalesced 256B wave-load
// (was: 64-line scatter, 5x HBM over-fetch => FETCH_SIZE 750MB vs 151MB
// ideal, ~2500 cyc/step). Serial step now: 1 coalesced load (8-deep ring)
// + 16 uniform ds_read_b128 + 32 v_pk_fma_f32.
//
// Buffers (ws stays exactly B*C*S*S floats = 151MB):
//   prelin(x   -> ws  )   A1 = W1*x + b1 + b2   (p=0 slot: raw x row0)
//   scan  (ws  -> out )   hsT[b][c][w][h] written into `out` as scratch
//   prelin(out -> ws  )   A2 = W4*hs + b4 + b5  (A1 dead, overwrite ok)
//   scan  (ws  -> out )   final out[b][c][h][w] (hsT fully consumed by prelin)
//
// Index map (identical formulas both passes):
//   T input : T[((b*64+c)*S + p)*S + q]   (p = step dim, q = sequence id)
//   A output: A[((b*S + q)*S + p)*64 + o]
//   scan out: out[((b*64+o)*S + q)*S + step]  (STORE16: one 64B line/lane)

#define C64 64
#define S   384

typedef float v2f __attribute__((ext_vector_type(2)));

static __device__ __forceinline__ v2f mk2(float a, float b) {
    v2f r; r.x = a; r.y = b; return r;
}

// ---------------------------------------------------------------------------
// prelin: A[b][q][p][o] = sum_c W[o][c] * T[b][c][p][q] + bx[o] + by[o]  (p>=1)
//         A[b][q][0][o] = T[b][o][0][q]                                 (p==0)
// Thread = q (384/block). All T reads coalesced (lanes = consecutive q).
// Weights are wave-uniform loads (compiler promotes to s_load, K$-resident).
// ---------------------------------------------------------------------------
__global__ __launch_bounds__(S, 2)
void prelin_kernel(const float* __restrict__ T, float* __restrict__ A,
                   const float* __restrict__ W, const float* __restrict__ bx,
                   const float* __restrict__ by)
{
    const int p = blockIdx.x;
    const int b = blockIdx.y;
    const int q = threadIdx.x;

    if (p == 0) {
        // raw transpose copy of step-0 row: reads coalesced over q, each
        // thread writes its contiguous 256B out-vector as 16 dwordx4.
        const int tb = ((b * C64) * S) * S + q;            // + o*S*S
        float4* dst = (float4*)(A + ((b * S + q) * S) * C64);
#pragma unroll
        for (int og = 0; og < 16; ++og) {
            float4 t;
            t.x = T[tb + (4*og+0) * S*S];
            t.y = T[tb + (4*og+1) * S*S];
            t.z = T[tb + (4*og+2) * S*S];
            t.w = T[tb + (4*og+3) * S*S];
            dst[og] = t;
        }
        return;
    }

    // stage the 64-channel input vector for this (b,p,q) in registers
    v2f vv[32];
    {
        const int tb = ((b * C64) * S + p) * S + q;        // + c*S*S
#pragma unroll
        for (int i = 0; i < 32; ++i) {
            float e0 = T[tb + (2*i+0) * S*S];
            float e1 = T[tb + (2*i+1) * S*S];
            vv[i] = mk2(e0, e1);
        }
    }

    float4* dst = (float4*)(A + ((b * S + q) * S + p) * C64);
    for (int og = 0; og < 16; ++og) {       // runtime loop: keep I$ small
        float4 r;
#pragma unroll
        for (int j = 0; j < 4; ++j) {
            const int o = 4*og + j;
            const v2f* wr = (const v2f*)(W + o * C64);     // uniform -> s_load
            v2f a0 = mk2(0.f, 0.f), a1 = a0, a2 = a0, a3 = a0;
#pragma unroll
            for (int i = 0; i < 32; i += 4) {
                a0 = __builtin_elementwise_fma(wr[i+0], vv[i+0], a0);
                a1 = __builtin_elementwise_fma(wr[i+1], vv[i+1], a1);
                a2 = __builtin_elementwise_fma(wr[i+2], vv[i+2], a2);
                a3 = __builtin_elementwise_fma(wr[i+3], vv[i+3], a3);
            }
            v2f sv = (a0 + a1) + (a2 + a3);
            ((float*)&r)[j] = sv.x + sv.y + bx[o] + by[o];
        }
        dst[og] = r;
    }
}

// ---------------------------------------------------------------------------
// scan: v_h = relu(A[b][q][h][:] + Wr * v_{h-1}); one wave per (b,q), lane=o.
// Per-step global load is one coalesced dword (256B/wave), 8-deep ring.
// ---------------------------------------------------------------------------
__global__ __launch_bounds__(64, 2)
void scan_kernel(const float* __restrict__ A, float* __restrict__ out,
                 const float* __restrict__ Wr, int mode)
{
    __shared__ float vs[2][C64];   // recurrent state row (double-buffered)

    const int o = threadIdx.x;     // lane = channel
    const int g = blockIdx.x;      // 0..1535 : (b, q)
    const int b = g / S;
    const int q = g - b * S;

    // ---- recurrent weights row o into registers, PINNED ----
    v2f wb2[32];
    {
        const float4* B4 = (const float4*)(Wr + o * C64);
#pragma unroll
        for (int i = 0; i < 16; ++i) {
            float4 qb = B4[i];
            wb2[2*i+0] = mk2(qb.x, qb.y);
            wb2[2*i+1] = mk2(qb.z, qb.w);
        }
#pragma unroll
        for (int i = 0; i < 32; ++i)
            asm volatile("" : "+v"(wb2[i]));   // non-rematerializable
    }

    const int abase = ((b * S + q) * S) * C64 + o;   // + h*C64 (coalesced)
    const int outb  = ((b * C64 + o) * S + q) * S;   // + h (batched lines)

    // ---- step 0 init + 8-deep coalesced prefetch ring ----
    float v0 = A[abase];
    if (mode) v0 = fmaxf(v0, 0.0f);
    vs[1][o] = v0;

    float af[8];
#pragma unroll
    for (int h = 1; h <= 8; ++h) af[h & 7] = A[abase + h * C64];
    __builtin_amdgcn_wave_barrier();

    float ob[16];   // 16-step output batch: one full 64B line per lane
    ob[0] = v0;

    // One scan step. H = step index, PAR = H&1 (compile-time), IDX = ob slot.
#define STEP(H, PAR, IDX)                                                     \
    {                                                                         \
        const float a = af[(H) & 7];                                          \
        const float4* vq4 = (const float4*)&vs[PAR][0];                       \
        v2f a0 = mk2(a, 0.0f), a1 = mk2(0.f, 0.f);                            \
        v2f a2 = mk2(0.f, 0.f), a3 = mk2(0.f, 0.f);                           \
        _Pragma("unroll")                                                     \
        for (int i = 0; i < 8; ++i) {                                         \
            float4 vq = vq4[2*i+0];   /* wave-broadcast LDS reads */          \
            float4 vr = vq4[2*i+1];                                           \
            a0 = __builtin_elementwise_fma(wb2[4*i+0], mk2(vq.x,vq.y), a0);   \
            a1 = __builtin_elementwise_fma(wb2[4*i+1], mk2(vq.z,vq.w), a1);   \
            a2 = __builtin_elementwise_fma(wb2[4*i+2], mk2(vr.x,vr.y), a2);   \
            a3 = __builtin_elementwise_fma(wb2[4*i+3], mk2(vr.z,vr.w), a3);   \
        }                                                                     \
        v2f sv = (a0 + a1) + (a2 + a3);                                       \
        float vnew = fmaxf(sv.x + sv.y, 0.0f);                                \
        ob[IDX] = vnew;                                                       \
        vs[(PAR) ^ 1][o] = vnew;       /* state for step H+1 */               \
        int hn = (H) + 8; hn = (hn > S-1) ? (S-1) : hn;                       \
        af[(H) & 7] = A[abase + hn * C64];                                    \
        __builtin_amdgcn_wave_barrier();                                      \
    }

#define STORE16(BASE)                                                         \
    {                                                                         \
        float4 q0 = {ob[0],  ob[1],  ob[2],  ob[3]};                          \
        float4 q1 = {ob[4],  ob[5],  ob[6],  ob[7]};                          \
        float4 q2 = {ob[8],  ob[9],  ob[10], ob[11]};                         \
        float4 q3 = {ob[12], ob[13], ob[14], ob[15]};                         \
        float4* p = (float4*)(out + outb + (BASE));                           \
        p[0] = q0; p[1] = q1; p[2] = q2; p[3] = q3;                           \
    }

    // ---- peel: steps 1..15, store batch h=0..15 ----
    STEP( 1,1, 1) STEP( 2,0, 2) STEP( 3,1, 3) STEP( 4,0, 4)
    STEP( 5,1, 5) STEP( 6,0, 6) STEP( 7,1, 7) STEP( 8,0, 8)
    STEP( 9,1, 9) STEP(10,0,10) STEP(11,1,11) STEP(12,0,12)
    STEP(13,1,13) STEP(14,0,14) STEP(15,1,15)
    STORE16(0)

    // ---- main: k = 1..23, steps 16k..16k+15 ----
    for (int k = 1; k < 24; ++k) {
        const int h0 = 16 * k;
        STEP(h0+ 0,0, 0) STEP(h0+ 1,1, 1) STEP(h0+ 2,0, 2) STEP(h0+ 3,1, 3)
        STEP(h0+ 4,0, 4) STEP(h0+ 5,1, 5) STEP(h0+ 6,0, 6) STEP(h0+ 7,1, 7)
        STEP(h0+ 8,0, 8) STEP(h0+ 9,1, 9) STEP(h0+10,0,10) STEP(h0+11,1,11)
        STEP(h0+12,0,12) STEP(h0+13,1,13) STEP(h0+14,0,14) STEP(h0+15,1,15)
        STORE16(h0)
    }
#undef STEP
#undef STORE16
}

extern "C" void kernel_launch(void* const* d_in, const int* in_sizes, int n_in,
                              void* d_out, int out_size, void* d_ws, size_t ws_size,
                              hipStream_t stream) {
    const float* x  = (const float*)d_in[0];
    const float* W1 = (const float*)d_in[1];
    const float* b1 = (const float*)d_in[2];
    const float* W2 = (const float*)d_in[3];
    const float* b2 = (const float*)d_in[4];
    const float* W4 = (const float*)d_in[5];
    const float* b4 = (const float*)d_in[6];
    const float* W5 = (const float*)d_in[7];
    const float* b5 = (const float*)d_in[8];
    float* out = (float*)d_out;
    float* ws  = (float*)d_ws;     // B*S*S*C floats (same size as before)

    dim3 pgrid(S, 4), pblock(S);
    dim3 sgrid(4 * S), sblock(C64);

    // Pass 1 (vertical, step dim = h): A1 = W1*x + b1 + b2  -> ws
    prelin_kernel<<<pgrid, pblock, 0, stream>>>(x, ws, W1, b1, b2);
    // scan1: hsT[b][c][w][h] -> out (scratch)
    scan_kernel<<<sgrid, sblock, 0, stream>>>(ws, out, W2, 0);
    // Pass 2 (horizontal, step dim = w): A2 = W4*hs + b4 + b5 -> ws
    prelin_kernel<<<pgrid, pblock, 0, stream>>>(out, ws, W4, b4, b5);
    // scan2: final out[b][c][h][w]
    scan_kernel<<<sgrid, sblock, 0, stream>>>(ws, out, W5, 1);
}

// Round 2
// 777.451 us; speedup vs baseline: 1.1928x; 1.0655x over previous
//
#include <hip/hip_runtime.h>

// UAG-RNN 4-neighbor, two directional scans — round 5.
//
// Round-5 changes (from rocprof round-1):
//  * prelin: WRITE_SIZE was 379MB vs 151MB ideal (lane=q scatter stores,
//    16B partial lines). New: one-wave blocks, 64-q tile, LDS transpose
//    os[64][68] (b128 in/out at baseline bank throughput), global stores
//    are full-64B-line coalesced dwordx4. Input vector pinned in VGPRs
//    (round-1 VGPR_Count=48 proved it was being re-loaded).
//  * scan: per-step LDS round trip (write->barrier->16 broadcast b128,
//    ~1130 cyc/step measured) replaced by 64x v_readlane broadcast of the
//    previous state into SGPRs feeding v_fmac directly. No LDS at all.
//
// Buffers (ws = B*C*S*S floats, unchanged):
//   prelin(x   -> ws )  A1 = W1*x + b1 + b2  (p=0 slot: raw row 0)
//   scan  (ws  -> out)  hsT[b][c][w][h] into `out` (scratch)
//   prelin(out -> ws )  A2 = W4*hs + b4 + b5
//   scan  (ws  -> out)  final out[b][c][h][w]
//
// Index map:
//   T input : T[((b*64+c)*S + p)*S + q]   (p = step dim, q = sequence id)
//   A output: A[((b*S + q)*S + p)*64 + o]
//   scan out: out[((b*64+o)*S + q)*S + step]

#define C64 64
#define S   384

typedef float v2f __attribute__((ext_vector_type(2)));

static __device__ __forceinline__ v2f mk2(float a, float b) {
    v2f r; r.x = a; r.y = b; return r;
}

// ---------------------------------------------------------------------------
// prelin: A[b][q][p][o] = sum_c W[o][c]*T[b][c][p][q] + bx[o] + by[o]  (p>=1)
//         A[b][q][0][o] = T[b][o][0][q]                                (p==0)
// One wave per (b, p, 64-q tile). Loads coalesced (lane=q), weights stream
// through SGPRs (uniform), outputs transposed via LDS so stores are
// full-line coalesced dwordx4.
// ---------------------------------------------------------------------------
__global__ __launch_bounds__(64, 4)
void prelin_kernel(const float* __restrict__ T, float* __restrict__ A,
                   const float* __restrict__ W, const float* __restrict__ bx,
                   const float* __restrict__ by)
{
    __shared__ float os[C64][68];   // 68-float rows: 16B-aligned, conflict-ok
    const int p  = blockIdx.x;
    const int q0 = blockIdx.y * 64;
    const int b  = blockIdx.z;
    const int l  = threadIdx.x;     // load/compute: lane = q ; store: see map
    const int q  = q0 + l;

    // ---- load channel vector for (b,p,q), lane-coalesced, PINNED ----
    v2f vv2[32];
    {
        const int tb = ((b * C64) * S + p) * S + q;        // + c*S*S
#pragma unroll
        for (int i = 0; i < 32; ++i) {
            float e0 = T[tb + (2*i+0) * S*S];
            float e1 = T[tb + (2*i+1) * S*S];
            vv2[i] = mk2(e0, e1);
        }
#pragma unroll
        for (int i = 0; i < 32; ++i)
            asm volatile("" : "+v"(vv2[i]));   // keep resident, no re-load
    }

    if (p == 0) {
        // raw pass-through of step-0 row
#pragma unroll
        for (int i = 0; i < 16; ++i) {
            float4 r;
            r.x = vv2[2*i+0].x; r.y = vv2[2*i+0].y;
            r.z = vv2[2*i+1].x; r.w = vv2[2*i+1].y;
            *(float4*)&os[l][4*i] = r;
        }
    } else {
        for (int og = 0; og < 16; ++og) {   // runtime loop: keep I$ small
            float4 r;
#pragma unroll
            for (int j = 0; j < 4; ++j) {
                const int o = og*4 + j;
                const v2f* wr = (const v2f*)(W + o * C64); // uniform -> s_load
                v2f a0 = mk2(0.f,0.f), a1 = a0, a2 = a0, a3 = a0;
#pragma unroll
                for (int i = 0; i < 32; i += 4) {
                    a0 = __builtin_elementwise_fma(wr[i+0], vv2[i+0], a0);
                    a1 = __builtin_elementwise_fma(wr[i+1], vv2[i+1], a1);
                    a2 = __builtin_elementwise_fma(wr[i+2], vv2[i+2], a2);
                    a3 = __builtin_elementwise_fma(wr[i+3], vv2[i+3], a3);
                }
                v2f sv = (a0 + a1) + (a2 + a3);
                ((float*)&r)[j] = sv.x + sv.y + bx[o] + by[o];
            }
            *(float4*)&os[l][4*og] = r;     // b128, baseline bank throughput
        }
    }
    __syncthreads();   // 1 wave: cheap; orders ds_write -> ds_read

    // ---- store: instr k covers 16 q's x 16B each, all full 64B lines ----
#pragma unroll
    for (int k = 0; k < 16; ++k) {
        const int qq = 16*(k & 3) + (l >> 2);
        const int oo = 16*(k >> 2) + 4*(l & 3);
        float4 v = *(const float4*)&os[qq][oo];
        *(float4*)(A + (((b*S + (q0+qq))*S + p) * C64 + oo)) = v;
    }
}

// ---------------------------------------------------------------------------
// scan: v_h = relu(A[b][q][h][:] + Wr * v_{h-1}); one wave per (b,q), lane=o.
// State broadcast via v_readlane -> SGPR -> v_fmac (no LDS, no barrier).
// ---------------------------------------------------------------------------
__global__ __launch_bounds__(64, 2)
void scan_kernel(const float* __restrict__ A, float* __restrict__ out,
                 const float* __restrict__ Wr, int mode)
{
    const int o = threadIdx.x;     // lane = channel
    const int g = blockIdx.x;      // 0..1535 : (b, q)
    const int b = g / S;
    const int q = g - b * S;

    // ---- recurrent weight row o in VGPRs, PINNED ----
    float wv[64];
    {
        const float4* B4 = (const float4*)(Wr + o * C64);
#pragma unroll
        for (int i = 0; i < 16; ++i) {
            float4 qb = B4[i];
            wv[4*i+0] = qb.x; wv[4*i+1] = qb.y;
            wv[4*i+2] = qb.z; wv[4*i+3] = qb.w;
        }
#pragma unroll
        for (int i = 0; i < 64; ++i)
            asm volatile("" : "+v"(wv[i]));
    }

    const int abase = ((b * S + q) * S) * C64 + o;   // + h*C64 (coalesced)
    const int outb  = ((b * C64 + o) * S + q) * S;   // + h (batched lines)

    // ---- step 0 init + 8-deep coalesced prefetch ring ----
    float v0 = A[abase];
    if (mode) v0 = fmaxf(v0, 0.0f);
    float vprev = v0;              // lane o holds channel o of the state

    float af[8];
#pragma unroll
    for (int h = 1; h <= 8; ++h) af[h & 7] = A[abase + h * C64];

    float ob[16];   // 16-step output batch: one full 64B line per lane
    ob[0] = v0;

    // One scan step: broadcast prev state via readlane, 64 fmac, relu.
#define STEP(H, IDX)                                                          \
    {                                                                         \
        float acc0 = af[(H) & 7], acc1 = 0.f, acc2 = 0.f, acc3 = 0.f;         \
        _Pragma("unroll")                                                     \
        for (int c = 0; c < 16; ++c) {                                        \
            float s0 = __uint_as_float(                                       \
                __builtin_amdgcn_readlane(__float_as_uint(vprev), 4*c+0));    \
            float s1 = __uint_as_float(                                       \
                __builtin_amdgcn_readlane(__float_as_uint(vprev), 4*c+1));    \
            float s2 = __uint_as_float(                                       \
                __builtin_amdgcn_readlane(__float_as_uint(vprev), 4*c+2));    \
            float s3 = __uint_as_float(                                       \
                __builtin_amdgcn_readlane(__float_as_uint(vprev), 4*c+3));    \
            acc0 = fmaf(wv[4*c+0], s0, acc0);                                 \
            acc1 = fmaf(wv[4*c+1], s1, acc1);                                 \
            acc2 = fmaf(wv[4*c+2], s2, acc2);                                 \
            acc3 = fmaf(wv[4*c+3], s3, acc3);                                 \
        }                                                                     \
        float vnew = fmaxf((acc0 + acc1) + (acc2 + acc3), 0.0f);              \
        ob[IDX] = vnew;                                                       \
        vprev = vnew;                                                         \
        int hn = (H) + 8; hn = (hn > S-1) ? (S-1) : hn;                       \
        af[(H) & 7] = A[abase + hn * C64];                                    \
    }

#define STORE16(BASE)                                                         \
    {                                                                         \
        float4 q0v = {ob[0],  ob[1],  ob[2],  ob[3]};                         \
        float4 q1v = {ob[4],  ob[5],  ob[6],  ob[7]};                         \
        float4 q2v = {ob[8],  ob[9],  ob[10], ob[11]};                        \
        float4 q3v = {ob[12], ob[13], ob[14], ob[15]};                        \
        float4* pp = (float4*)(out + outb + (BASE));                          \
        pp[0] = q0v; pp[1] = q1v; pp[2] = q2v; pp[3] = q3v;                   \
    }

    // ---- peel: steps 1..15, store batch h=0..15 ----
    STEP( 1, 1) STEP( 2, 2) STEP( 3, 3) STEP( 4, 4)
    STEP( 5, 5) STEP( 6, 6) STEP( 7, 7) STEP( 8, 8)
    STEP( 9, 9) STEP(10,10) STEP(11,11) STEP(12,12)
    STEP(13,13) STEP(14,14) STEP(15,15)
    STORE16(0)

    // ---- main: k = 1..23, steps 16k..16k+15 ----
    for (int k = 1; k < 24; ++k) {
        const int h0 = 16 * k;
        STEP(h0+ 0, 0) STEP(h0+ 1, 1) STEP(h0+ 2, 2) STEP(h0+ 3, 3)
        STEP(h0+ 4, 4) STEP(h0+ 5, 5) STEP(h0+ 6, 6) STEP(h0+ 7, 7)
        STEP(h0+ 8, 8) STEP(h0+ 9, 9) STEP(h0+10,10) STEP(h0+11,11)
        STEP(h0+12,12) STEP(h0+13,13) STEP(h0+14,14) STEP(h0+15,15)
        STORE16(h0)
    }
#undef STEP
#undef STORE16
}

extern "C" void kernel_launch(void* const* d_in, const int* in_sizes, int n_in,
                              void* d_out, int out_size, void* d_ws, size_t ws_size,
                              hipStream_t stream) {
    const float* x  = (const float*)d_in[0];
    const float* W1 = (const float*)d_in[1];
    const float* b1 = (const float*)d_in[2];
    const float* W2 = (const float*)d_in[3];
    const float* b2 = (const float*)d_in[4];
    const float* W4 = (const float*)d_in[5];
    const float* b4 = (const float*)d_in[6];
    const float* W5 = (const float*)d_in[7];
    const float* b5 = (const float*)d_in[8];
    float* out = (float*)d_out;
    float* ws  = (float*)d_ws;     // B*S*S*C floats

    dim3 pgrid(S, 6, 4), pblock(C64);   // p, q-tile, b — 9216 one-wave blocks
    dim3 sgrid(4 * S),   sblock(C64);   // 1536 waves, one per (b, q)

    // Pass 1 (vertical, step dim = h): A1 = W1*x + b1 + b2  -> ws
    prelin_kernel<<<pgrid, pblock, 0, stream>>>(x, ws, W1, b1, b2);
    // scan1: hsT[b][c][w][h] -> out (scratch)
    scan_kernel<<<sgrid, sblock, 0, stream>>>(ws, out, W2, 0);
    // Pass 2 (horizontal, step dim = w): A2 = W4*hs + b4 + b5 -> ws
    prelin_kernel<<<pgrid, pblock, 0, stream>>>(out, ws, W4, b4, b5);
    // scan2: final out[b][c][h][w]
    scan_kernel<<<sgrid, sblock, 0, stream>>>(ws, out, W5, 1);
}

// Round 3
// 768.425 us; speedup vs baseline: 1.2068x; 1.0117x over previous
//
#include <hip/hip_runtime.h>

// UAG-RNN 4-neighbor — round 6: 3-kernel fused pipeline.
//
//  prelin (x -> out):   A1[b][w][h][o] = W1*x[:,h,w] + b1 + b2  (h>=1)
//                       A1[b][w][0][o] = x[o][0][w]             (raw row 0)
//                       2 p-slices per wave (latency pipeline), LDS-transposed
//                       full-line stores.
//  scan1 (out -> ws):   vertical recurrence v_h = relu(A1 + W2*v_{h-1});
//                       FUSED pass-2 prelinear: the same LDS broadcast of
//                       v_{h-1} feeds W4*v+b4+b5, stored straight into
//                       A2[b][h][w][o] as ONE coalesced 256B store per step.
//                       (This deletes the old prelin2 dispatch entirely.)
//                       w==0 wave stores raw v (pass-2's p=0 slot).
//  scan2 (ws -> out):   horizontal recurrence v_w = relu(A2 + W5*v_{w-1});
//                       TWO chains per wave (fills the ~800cyc/step stall
//                       envelope measured in r1/r2), batched 16-step stores.
//
// Weights pinned as v2f (round-0 proven: VGPR=128 held; round-2 scalar-float
// pin failed, VGPR=60). Broadcast via uniform-address ds_read_b128 (round 1/2
// showed readlane == LDS in cost; LDS has 2.6x fewer instructions).

#define C64 64
#define S   384

typedef float v2f __attribute__((ext_vector_type(2)));

static __device__ __forceinline__ v2f mk2(float a, float b) {
    v2f r; r.x = a; r.y = b; return r;
}

// ---------------------------------------------------------------------------
// prelin: two p-slices per wave, weight stream via s_load (uniform), output
// transposed through LDS so every store instruction covers full 64B lines.
// ---------------------------------------------------------------------------
__global__ __launch_bounds__(64, 2)
void prelin_kernel(const float* __restrict__ T, float* __restrict__ Aout,
                   const float* __restrict__ W, const float* __restrict__ bx,
                   const float* __restrict__ by)
{
    __shared__ float os[C64][68];
    const int p0 = blockIdx.x * 2;
    const int q0 = blockIdx.y * 64;
    const int b  = blockIdx.z;
    const int l  = threadIdx.x;
    const int q  = q0 + l;

    // both p-slices' channel vectors loaded up front (128 coalesced dwords)
    v2f va[32], vb[32];
    {
        const int tbA = ((b * C64) * S + p0) * S + q;      // + c*S*S
#pragma unroll
        for (int i = 0; i < 32; ++i)
            va[i] = mk2(T[tbA + (2*i+0)*S*S], T[tbA + (2*i+1)*S*S]);
        const int tbB = tbA + S;                           // p0+1
#pragma unroll
        for (int i = 0; i < 32; ++i)
            vb[i] = mk2(T[tbB + (2*i+0)*S*S], T[tbB + (2*i+1)*S*S]);
#pragma unroll
        for (int i = 0; i < 32; ++i)
            asm volatile("" : "+v"(va[i]));   // pin A now; B pinned later so
    }                                         // its wait hides under phase A

#define PMATVEC(VV)                                                           \
    for (int og = 0; og < 16; ++og) {                                         \
        float4 r;                                                             \
        _Pragma("unroll")                                                     \
        for (int j = 0; j < 4; ++j) {                                         \
            const int o4 = og*4 + j;                                          \
            const v2f* wr = (const v2f*)(W + o4 * C64);                       \
            v2f a0 = mk2(0.f,0.f), a1 = a0, a2 = a0, a3 = a0;                 \
            _Pragma("unroll")                                                 \
            for (int i = 0; i < 32; i += 4) {                                 \
                a0 = __builtin_elementwise_fma(wr[i+0], VV[i+0], a0);         \
                a1 = __builtin_elementwise_fma(wr[i+1], VV[i+1], a1);         \
                a2 = __builtin_elementwise_fma(wr[i+2], VV[i+2], a2);         \
                a3 = __builtin_elementwise_fma(wr[i+3], VV[i+3], a3);         \
            }                                                                 \
            v2f sv = (a0 + a1) + (a2 + a3);                                   \
            ((float*)&r)[j] = sv.x + sv.y + bx[o4] + by[o4];                  \
        }                                                                     \
        *(float4*)&os[l][4*og] = r;                                           \
    }

#define PPASS(VV)                                                             \
    _Pragma("unroll")                                                         \
    for (int i = 0; i < 16; ++i) {                                            \
        float4 r;                                                             \
        r.x = VV[2*i].x; r.y = VV[2*i].y;                                     \
        r.z = VV[2*i+1].x; r.w = VV[2*i+1].y;                                 \
        *(float4*)&os[l][4*i] = r;                                            \
    }

#define PSTORE(P)                                                             \
    _Pragma("unroll")                                                         \
    for (int k = 0; k < 16; ++k) {                                            \
        const int qq = 16*(k & 3) + (l >> 2);                                 \
        const int oo = 16*(k >> 2) + 4*(l & 3);                               \
        *(float4*)(Aout + (((b*S + (q0+qq))*S + (P)) * C64 + oo)) =           \
            *(const float4*)&os[qq][oo];                                      \
    }

    // phase A
    if (p0 == 0) { PPASS(va) } else { PMATVEC(va) }
    __syncthreads();
    PSTORE(p0)
#pragma unroll
    for (int i = 0; i < 32; ++i)
        asm volatile("" : "+v"(vb[i]));       // pin B (loads long in flight)
    __syncthreads();
    // phase B (p0+1 >= 1 always: matvec)
    PMATVEC(vb)
    __syncthreads();
    PSTORE(p0 + 1)
#undef PMATVEC
#undef PPASS
#undef PSTORE
}

// ---------------------------------------------------------------------------
// scan1: vertical recurrence + fused W4 prelinear store (replaces prelin2).
// One wave per (b, w). Per step: 16 uniform ds_read_b128 broadcast v_{h-1},
// feed BOTH W2 (recurrence) and W4 (A2 store) pk_fma chains; one coalesced
// 256B global store; 8-deep coalesced prefetch ring on A1.
// ---------------------------------------------------------------------------
__global__ __launch_bounds__(64, 2)
void scan1_kernel(const float* __restrict__ A,   // A1 (in `out`)
                  float* __restrict__ A2,        // ws
                  const float* __restrict__ W2,
                  const float* __restrict__ W4,
                  const float* __restrict__ b4,
                  const float* __restrict__ b5)
{
    __shared__ float vs[2][C64];
    const int o = threadIdx.x;
    const int g = blockIdx.x;      // (b, w)
    const int b = g / S;
    const int w = g - b * S;
    const bool w_is0 = (w == 0);

    v2f w2a[32], w4a[32];
    {
        const float4* P2 = (const float4*)(W2 + o * C64);
        const float4* P4 = (const float4*)(W4 + o * C64);
#pragma unroll
        for (int i = 0; i < 16; ++i) {
            float4 u2 = P2[i], u4 = P4[i];
            w2a[2*i+0] = mk2(u2.x, u2.y); w2a[2*i+1] = mk2(u2.z, u2.w);
            w4a[2*i+0] = mk2(u4.x, u4.y); w4a[2*i+1] = mk2(u4.z, u4.w);
        }
#pragma unroll
        for (int i = 0; i < 32; ++i) {
            asm volatile("" : "+v"(w2a[i]));
            asm volatile("" : "+v"(w4a[i]));
        }
    }
    const float bias45 = b4[o] + b5[o];

    const int abase = ((b * S + w) * S) * C64 + o;   // A1 + h*C64
    const int sbase = (b * S * S + w) * C64 + o;     // A2 + h*(S*C64)

    float vprev = A[abase];        // v_0 (raw row 0, no relu)
    vs[1][o] = vprev;
    float af[8];
#pragma unroll
    for (int h = 1; h <= 8; ++h) af[h & 7] = A[abase + h * C64];
    __builtin_amdgcn_wave_barrier();

#define S1STEP(H, SLOT, PAR, REFILL)                                          \
    {                                                                         \
        const float4* vq4 = (const float4*)&vs[PAR][0];                       \
        v2f aV0 = mk2(af[SLOT], 0.f), aV1 = mk2(0.f,0.f),                     \
            aV2 = mk2(0.f,0.f),       aV3 = mk2(0.f,0.f);                     \
        v2f aU0 = mk2(bias45, 0.f),   aU1 = mk2(0.f,0.f),                     \
            aU2 = mk2(0.f,0.f),       aU3 = mk2(0.f,0.f);                     \
        _Pragma("unroll")                                                     \
        for (int i = 0; i < 8; ++i) {                                         \
            float4 r0 = vq4[2*i], r1 = vq4[2*i+1];                            \
            v2f x0 = mk2(r0.x, r0.y), x1 = mk2(r0.z, r0.w);                   \
            v2f x2 = mk2(r1.x, r1.y), x3 = mk2(r1.z, r1.w);                   \
            aV0 = __builtin_elementwise_fma(w2a[4*i+0], x0, aV0);             \
            aV1 = __builtin_elementwise_fma(w2a[4*i+1], x1, aV1);             \
            aV2 = __builtin_elementwise_fma(w2a[4*i+2], x2, aV2);             \
            aV3 = __builtin_elementwise_fma(w2a[4*i+3], x3, aV3);             \
            aU0 = __builtin_elementwise_fma(w4a[4*i+0], x0, aU0);             \
            aU1 = __builtin_elementwise_fma(w4a[4*i+1], x1, aU1);             \
            aU2 = __builtin_elementwise_fma(w4a[4*i+2], x2, aU2);             \
            aU3 = __builtin_elementwise_fma(w4a[4*i+3], x3, aU3);             \
        }                                                                     \
        v2f sV = (aV0 + aV1) + (aV2 + aV3);                                   \
        v2f sU = (aU0 + aU1) + (aU2 + aU3);                                   \
        float vnew = fmaxf(sV.x + sV.y, 0.0f);                                \
        float uu   = sU.x + sU.y;                                             \
        A2[sbase + ((H) - 1) * (S * C64)] = w_is0 ? vprev : uu;               \
        vs[(PAR) ^ 1][o] = vnew;                                              \
        vprev = vnew;                                                         \
        if (REFILL) af[SLOT] = A[abase + ((H) + 8) * C64];                    \
        __builtin_amdgcn_wave_barrier();                                      \
    }

    // main: kb=0..45 covers H=1..368, refill h+8 <= 376 always in range
    for (int kb = 0; kb < 46; ++kb) {
        const int h0 = 8 * kb + 1;
        S1STEP(h0+0, 1, 1, 1) S1STEP(h0+1, 2, 0, 1)
        S1STEP(h0+2, 3, 1, 1) S1STEP(h0+3, 4, 0, 1)
        S1STEP(h0+4, 5, 1, 1) S1STEP(h0+5, 6, 0, 1)
        S1STEP(h0+6, 7, 1, 1) S1STEP(h0+7, 0, 0, 1)
    }
    // tail: H=369..383 (refill only while H+8 <= 383)
    S1STEP(369, 1, 1, 1) S1STEP(370, 2, 0, 1) S1STEP(371, 3, 1, 1)
    S1STEP(372, 4, 0, 1) S1STEP(373, 5, 1, 1) S1STEP(374, 6, 0, 1)
    S1STEP(375, 7, 1, 1) S1STEP(376, 0, 0, 0) S1STEP(377, 1, 1, 0)
    S1STEP(378, 2, 0, 0) S1STEP(379, 3, 1, 0) S1STEP(380, 4, 0, 0)
    S1STEP(381, 5, 1, 0) S1STEP(382, 6, 0, 0) S1STEP(383, 7, 1, 0)
#undef S1STEP

    // epilogue: store A2 row for h=383 from v_383 (in vs[0])
    {
        const float4* vq4 = (const float4*)&vs[0][0];
        v2f aU0 = mk2(bias45, 0.f), aU1 = mk2(0.f,0.f),
            aU2 = mk2(0.f,0.f),     aU3 = mk2(0.f,0.f);
#pragma unroll
        for (int i = 0; i < 8; ++i) {
            float4 r0 = vq4[2*i], r1 = vq4[2*i+1];
            aU0 = __builtin_elementwise_fma(w4a[4*i+0], mk2(r0.x,r0.y), aU0);
            aU1 = __builtin_elementwise_fma(w4a[4*i+1], mk2(r0.z,r0.w), aU1);
            aU2 = __builtin_elementwise_fma(w4a[4*i+2], mk2(r1.x,r1.y), aU2);
            aU3 = __builtin_elementwise_fma(w4a[4*i+3], mk2(r1.z,r1.w), aU3);
        }
        v2f sU = (aU0 + aU1) + (aU2 + aU3);
        float uu = sU.x + sU.y;
        A2[sbase + 383 * (S * C64)] = w_is0 ? vprev : uu;
    }
}

// ---------------------------------------------------------------------------
// scan2: horizontal recurrence, TWO chains per wave. Reads A2 coalesced
// (256B/step/chain, 8-deep rings), writes final out in 16-step batches.
// ---------------------------------------------------------------------------
__global__ __launch_bounds__(64, 2)
void scan2_kernel(const float* __restrict__ A2,  // ws
                  float* __restrict__ out,
                  const float* __restrict__ W5)
{
    __shared__ float vsA[2][C64], vsB[2][C64];
    const int o  = threadIdx.x;
    const int g  = blockIdx.x;           // 0..767
    const int gA = g, gB = g + 768;
    const int bA = gA / S, qA = gA - bA * S;
    const int bB = gB / S, qB = gB - bB * S;

    v2f wva[32];
    {
        const float4* P5 = (const float4*)(W5 + o * C64);
#pragma unroll
        for (int i = 0; i < 16; ++i) {
            float4 u5 = P5[i];
            wva[2*i+0] = mk2(u5.x, u5.y); wva[2*i+1] = mk2(u5.z, u5.w);
        }
#pragma unroll
        for (int i = 0; i < 32; ++i)
            asm volatile("" : "+v"(wva[i]));
    }

    const int abA = ((bA * S + qA) * S) * C64 + o;
    const int abB = ((bB * S + qB) * S) * C64 + o;
    const int obA_ = ((bA * C64 + o) * S + qA) * S;
    const int obB_ = ((bB * C64 + o) * S + qB) * S;

    float vA = fmaxf(A2[abA], 0.0f);     // mode=1: relu on column 0
    float vB = fmaxf(A2[abB], 0.0f);
    vsA[1][o] = vA; vsB[1][o] = vB;

    float afA[8], afB[8];
#pragma unroll
    for (int h = 1; h <= 8; ++h) {
        afA[h & 7] = A2[abA + h * C64];
        afB[h & 7] = A2[abB + h * C64];
    }
    __builtin_amdgcn_wave_barrier();

    float obA[16], obB[16];
    obA[0] = vA; obB[0] = vB;

#define S2STEP(H, SLOT, PAR, IDX, REFILL)                                     \
    {                                                                         \
        const float4* pa = (const float4*)&vsA[PAR][0];                       \
        const float4* pb = (const float4*)&vsB[PAR][0];                       \
        v2f aA0 = mk2(afA[SLOT], 0.f), aA1 = mk2(0.f,0.f),                    \
            aA2 = mk2(0.f,0.f),        aA3 = mk2(0.f,0.f);                    \
        v2f aB0 = mk2(afB[SLOT], 0.f), aB1 = mk2(0.f,0.f),                    \
            aB2 = mk2(0.f,0.f),        aB3 = mk2(0.f,0.f);                    \
        _Pragma("unroll")                                                     \
        for (int i = 0; i < 8; ++i) {                                         \
            float4 r0 = pa[2*i], r1 = pa[2*i+1];                              \
            float4 t0 = pb[2*i], t1 = pb[2*i+1];                              \
            aA0 = __builtin_elementwise_fma(wva[4*i+0], mk2(r0.x,r0.y), aA0); \
            aA1 = __builtin_elementwise_fma(wva[4*i+1], mk2(r0.z,r0.w), aA1); \
            aA2 = __builtin_elementwise_fma(wva[4*i+2], mk2(r1.x,r1.y), aA2); \
            aA3 = __builtin_elementwise_fma(wva[4*i+3], mk2(r1.z,r1.w), aA3); \
            aB0 = __builtin_elementwise_fma(wva[4*i+0], mk2(t0.x,t0.y), aB0); \
            aB1 = __builtin_elementwise_fma(wva[4*i+1], mk2(t0.z,t0.w), aB1); \
            aB2 = __builtin_elementwise_fma(wva[4*i+2], mk2(t1.x,t1.y), aB2); \
            aB3 = __builtin_elementwise_fma(wva[4*i+3], mk2(t1.z,t1.w), aB3); \
        }                                                                     \
        v2f sA = (aA0 + aA1) + (aA2 + aA3);                                   \
        v2f sB = (aB0 + aB1) + (aB2 + aB3);                                   \
        float nA = fmaxf(sA.x + sA.y, 0.0f);                                  \
        float nB = fmaxf(sB.x + sB.y, 0.0f);                                  \
        obA[IDX] = nA; obB[IDX] = nB;                                         \
        vsA[(PAR) ^ 1][o] = nA; vsB[(PAR) ^ 1][o] = nB;                       \
        if (REFILL) {                                                         \
            afA[SLOT] = A2[abA + ((H) + 8) * C64];                            \
            afB[SLOT] = A2[abB + ((H) + 8) * C64];                            \
        }                                                                     \
        __builtin_amdgcn_wave_barrier();                                      \
    }

#define STORE16(ARR, BASEP, BASE)                                             \
    {                                                                         \
        float4 s0 = {ARR[0],  ARR[1],  ARR[2],  ARR[3]};                      \
        float4 s1 = {ARR[4],  ARR[5],  ARR[6],  ARR[7]};                      \
        float4 s2 = {ARR[8],  ARR[9],  ARR[10], ARR[11]};                     \
        float4 s3 = {ARR[12], ARR[13], ARR[14], ARR[15]};                     \
        float4* pp = (float4*)(out + (BASEP) + (BASE));                       \
        pp[0] = s0; pp[1] = s1; pp[2] = s2; pp[3] = s3;                       \
    }

    // peel: steps 1..15
    S2STEP( 1,1,1, 1,1) S2STEP( 2,2,0, 2,1) S2STEP( 3,3,1, 3,1)
    S2STEP( 4,4,0, 4,1) S2STEP( 5,5,1, 5,1) S2STEP( 6,6,0, 6,1)
    S2STEP( 7,7,1, 7,1) S2STEP( 8,0,0, 8,1) S2STEP( 9,1,1, 9,1)
    S2STEP(10,2,0,10,1) S2STEP(11,3,1,11,1) S2STEP(12,4,0,12,1)
    S2STEP(13,5,1,13,1) S2STEP(14,6,0,14,1) S2STEP(15,7,1,15,1)
    STORE16(obA, obA_, 0) STORE16(obB, obB_, 0)

    // main: k=1..22 -> steps 16..367 (refill h+8 <= 375 always safe)
    for (int k = 1; k < 23; ++k) {
        const int h0 = 16 * k;
        S2STEP(h0+ 0,0,0, 0,1) S2STEP(h0+ 1,1,1, 1,1)
        S2STEP(h0+ 2,2,0, 2,1) S2STEP(h0+ 3,3,1, 3,1)
        S2STEP(h0+ 4,4,0, 4,1) S2STEP(h0+ 5,5,1, 5,1)
        S2STEP(h0+ 6,6,0, 6,1) S2STEP(h0+ 7,7,1, 7,1)
        S2STEP(h0+ 8,0,0, 8,1) S2STEP(h0+ 9,1,1, 9,1)
        S2STEP(h0+10,2,0,10,1) S2STEP(h0+11,3,1,11,1)
        S2STEP(h0+12,4,0,12,1) S2STEP(h0+13,5,1,13,1)
        S2STEP(h0+14,6,0,14,1) S2STEP(h0+15,7,1,15,1)
        STORE16(obA, obA_, h0) STORE16(obB, obB_, h0)
    }
    // tail: steps 368..383
    S2STEP(368,0,0, 0,1) S2STEP(369,1,1, 1,1) S2STEP(370,2,0, 2,1)
    S2STEP(371,3,1, 3,1) S2STEP(372,4,0, 4,1) S2STEP(373,5,1, 5,1)
    S2STEP(374,6,0, 6,1) S2STEP(375,7,1, 7,1) S2STEP(376,0,0, 8,0)
    S2STEP(377,1,1, 9,0) S2STEP(378,2,0,10,0) S2STEP(379,3,1,11,0)
    S2STEP(380,4,0,12,0) S2STEP(381,5,1,13,0) S2STEP(382,6,0,14,0)
    S2STEP(383,7,1,15,0)
    STORE16(obA, obA_, 368) STORE16(obB, obB_, 368)
#undef S2STEP
#undef STORE16
}

extern "C" void kernel_launch(void* const* d_in, const int* in_sizes, int n_in,
                              void* d_out, int out_size, void* d_ws, size_t ws_size,
                              hipStream_t stream) {
    const float* x  = (const float*)d_in[0];
    const float* W1 = (const float*)d_in[1];
    const float* b1 = (const float*)d_in[2];
    const float* W2 = (const float*)d_in[3];
    const float* b2 = (const float*)d_in[4];
    const float* W4 = (const float*)d_in[5];
    const float* b4 = (const float*)d_in[6];
    const float* W5 = (const float*)d_in[7];
    const float* b5 = (const float*)d_in[8];
    float* out = (float*)d_out;
    float* ws  = (float*)d_ws;     // B*S*S*C floats

    // A1 -> out (scratch), A2 -> ws, final -> out. No buffer conflicts:
    // each dispatch reads one buffer and writes the other.
    prelin_kernel<<<dim3(S/2, 6, 4), dim3(C64), 0, stream>>>(x, out, W1, b1, b2);
    scan1_kernel<<<dim3(4 * S), dim3(C64), 0, stream>>>(out, ws, W2, W4, b4, b5);
    scan2_kernel<<<dim3(2 * S), dim3(C64), 0, stream>>>(ws, out, W5);
}

// Round 4
// 720.080 us; speedup vs baseline: 1.2878x; 1.0671x over previous
//
#include <hip/hip_runtime.h>

// UAG-RNN 4-neighbor — round 7: producer/consumer scan waves.
//
// Diagnosis r0-r3: every scan variant spilled its weight array (r2 VGPR=60
// for 64 pinned floats, r3 VGPR=88 for 128) -> per-step spill reloads are the
// ~1200-1800 cyc/step envelope. Fix: cap weights at 64 floats/wave.
//
//  scan kernels = 128-thread blocks, one chain per block:
//    wave0 (producer): ONLY the recurrence matrix resident (64 VGPR).
//      step: ds_read vs[par] (16 uniform b128) -> 16 v2f FMA -> relu ->
//            ds_write vs[par^1]. ZERO vmem. ~70 instrs, runtime loop.
//    wave1 (consumer): ONLY the second matrix (scan1) resident.
//      - prefetches A rows 7-deep into LDS ring xs (2-step register hold so
//        the vmcnt wait is ~600cy after issue, never blocking the step)
//      - scan1: computes fused A2 = W4*v+b4+b5, 256B coalesced store/step
//      - scan2: batches 32 output steps in LDS -> 128B/lane stores (full
//        write granule; fixes r2's 2x WRITE_SIZE amplification)
//    one __syncthreads per step (top-level, both waves -> legal).
//
// Buffers: prelin(x->out)=A1[b][w][h][o]; scan1(out->ws)=A2[b][h][w][o];
//          scan2(ws->out)=final.

#define C64 64
#define S   384

typedef float v2f __attribute__((ext_vector_type(2)));

static __device__ __forceinline__ v2f mk2(float a, float b) {
    v2f r; r.x = a; r.y = b; return r;
}

// ---------------------------------------------------------------------------
// prelin (r5 structure, known-good): A[b][q][p][o] = W*T[b][:][p][q]+bx+by
// (p>=1); p==0 slot = raw T row. Lane=q coalesced loads, LDS transpose,
// full-line stores. launch_bounds(64,2): VGPR cap 256 so the 64-float input
// vector has headroom to stay resident.
// ---------------------------------------------------------------------------
__global__ __launch_bounds__(64, 2)
void prelin_kernel(const float* __restrict__ T, float* __restrict__ A,
                   const float* __restrict__ W, const float* __restrict__ bx,
                   const float* __restrict__ by)
{
    __shared__ float os[C64][68];
    const int p  = blockIdx.x;
    const int q0 = blockIdx.y * 64;
    const int b  = blockIdx.z;
    const int l  = threadIdx.x;
    const int q  = q0 + l;

    v2f vv2[32];
    {
        const int tb = ((b * C64) * S + p) * S + q;        // + c*S*S
#pragma unroll
        for (int i = 0; i < 32; ++i) {
            float e0 = T[tb + (2*i+0) * S*S];
            float e1 = T[tb + (2*i+1) * S*S];
            vv2[i] = mk2(e0, e1);
        }
#pragma unroll
        for (int i = 0; i < 32; ++i)
            asm volatile("" : "+v"(vv2[i]));
    }

    if (p == 0) {
#pragma unroll
        for (int i = 0; i < 16; ++i) {
            float4 r;
            r.x = vv2[2*i+0].x; r.y = vv2[2*i+0].y;
            r.z = vv2[2*i+1].x; r.w = vv2[2*i+1].y;
            *(float4*)&os[l][4*i] = r;
        }
    } else {
        for (int og = 0; og < 16; ++og) {
            float4 r;
#pragma unroll
            for (int j = 0; j < 4; ++j) {
                const int o4 = og*4 + j;
                const v2f* wr = (const v2f*)(W + o4 * C64); // uniform->s_load
                v2f a0 = mk2(0.f,0.f), a1 = a0, a2 = a0, a3 = a0;
#pragma unroll
                for (int i = 0; i < 32; i += 4) {
                    a0 = __builtin_elementwise_fma(wr[i+0], vv2[i+0], a0);
                    a1 = __builtin_elementwise_fma(wr[i+1], vv2[i+1], a1);
                    a2 = __builtin_elementwise_fma(wr[i+2], vv2[i+2], a2);
                    a3 = __builtin_elementwise_fma(wr[i+3], vv2[i+3], a3);
                }
                v2f sv = (a0 + a1) + (a2 + a3);
                ((float*)&r)[j] = sv.x + sv.y + bx[o4] + by[o4];
            }
            *(float4*)&os[l][4*og] = r;
        }
    }
    __syncthreads();

#pragma unroll
    for (int k = 0; k < 16; ++k) {
        const int qq = 16*(k & 3) + (l >> 2);
        const int oo = 16*(k >> 2) + 4*(l & 3);
        *(float4*)(A + (((b*S + (q0+qq))*S + p) * C64 + oo)) =
            *(const float4*)&os[qq][oo];
    }
}

// ---------------------------------------------------------------------------
// shared FMA body: acc = bias-ish + M * vs_row   (16 v2f pk_fma, 4 chains)
// ---------------------------------------------------------------------------
#define MATVEC(DST, WREG, VQ4, INIT)                                          \
    float DST;                                                                \
    {                                                                         \
        v2f a0 = mk2((INIT), 0.f), a1 = mk2(0.f,0.f),                         \
            a2v = mk2(0.f,0.f),    a3 = mk2(0.f,0.f);                         \
        _Pragma("unroll")                                                     \
        for (int i = 0; i < 8; ++i) {                                         \
            float4 r0 = (VQ4)[2*i], r1 = (VQ4)[2*i+1];                        \
            a0  = __builtin_elementwise_fma(WREG[4*i+0], mk2(r0.x,r0.y), a0); \
            a1  = __builtin_elementwise_fma(WREG[4*i+1], mk2(r0.z,r0.w), a1); \
            a2v = __builtin_elementwise_fma(WREG[4*i+2], mk2(r1.x,r1.y), a2v);\
            a3  = __builtin_elementwise_fma(WREG[4*i+3], mk2(r1.z,r1.w), a3); \
        }                                                                     \
        v2f sv = (a0 + a1) + (a2v + a3);                                      \
        DST = sv.x + sv.y;                                                    \
    }

// ---------------------------------------------------------------------------
// scan1: vertical recurrence + fused W4 prelinear (A2) store.
// ---------------------------------------------------------------------------
__global__ __launch_bounds__(128, 2)
void scan1_kernel(const float* __restrict__ A,   // A1 (in `out`)
                  float* __restrict__ A2,        // ws
                  const float* __restrict__ W2,
                  const float* __restrict__ W4,
                  const float* __restrict__ b4,
                  const float* __restrict__ b5)
{
    __shared__ float vs[2][C64];   // state double-buffer
    __shared__ float xs[8][C64];   // A1-row prefetch ring (7-deep)

    const int t   = threadIdx.x;
    const int wid = t >> 6;
    const int o   = t & 63;
    const int g   = blockIdx.x;    // (b, w)
    const int b   = g / S;
    const int w   = g - b * S;

    const int abase = ((b * S + w) * S) * C64 + o;   // A1 + h*C64
    const int sbase = (b * S * S + w) * C64 + o;     // A2 + h*(S*C64)

    // per-wave weight row: wave0 -> W2, wave1 -> W4 (64 floats each)
    v2f wr2[32];
    {
        const float* Wsel = (wid == 0) ? W2 : W4;
        const float4* P = (const float4*)(Wsel + o * C64);
#pragma unroll
        for (int i = 0; i < 16; ++i) {
            float4 u = P[i];
            wr2[2*i+0] = mk2(u.x, u.y);
            wr2[2*i+1] = mk2(u.z, u.w);
        }
#pragma unroll
        for (int i = 0; i < 32; ++i) asm volatile("" : "+v"(wr2[i]));
    }

    float bias45 = 0.f, ldA = 0.f, ldB = 0.f;
    if (wid == 0) {
        vs[1][o] = A[abase];            // v_0 = raw row 0
    } else {
        bias45 = b4[o] + b5[o];
#pragma unroll
        for (int r = 1; r <= 7; ++r) xs[r][o] = A[abase + r * C64];
        ldA = A[abase + 8 * C64];       // row 8 -> xs at h=1
        ldB = A[abase + 9 * C64];       // row 9 -> xs at h=2
    }
    __syncthreads();

    // producer step: v_H = relu(A1[H] + W2*v_{H-1}); no vmem at all.
#define P1STEP(H, PAR)                                                        \
    {                                                                         \
        const float4* vq4 = (const float4*)&vs[PAR][0];                       \
        float aterm = xs[(H) & 7][o];                                         \
        MATVEC(sum_, wr2, vq4, aterm)                                         \
        vs[(PAR) ^ 1][o] = fmaxf(sum_, 0.0f);                                 \
    }
    // consumer step: u_{H-1} = W4*v_{H-1}+b45 -> A2 row H-1; stage row H+7;
    // issue load of row H+9 (2-step register hold).
#define C1STEP(H, PAR, LD)                                                    \
    {                                                                         \
        const float4* vq4 = (const float4*)&vs[PAR][0];                       \
        MATVEC(u_, wr2, vq4, bias45)                                          \
        if (w == 0) u_ = vs[PAR][o];                                          \
        A2[sbase + ((H) - 1) * (S * C64)] = u_;                               \
        xs[((H) + 7) & 7][o] = LD;                                            \
        int hn = (H) + 9; hn = (hn > S - 1) ? (S - 1) : hn;                   \
        LD = A[abase + hn * C64];                                             \
    }

    for (int h = 1; h <= S; h += 2) {
        if (wid == 0) { P1STEP(h, 1) } else { C1STEP(h, 1, ldA) }
        __syncthreads();
        if (wid == 0) { P1STEP(h + 1, 0) } else { C1STEP(h + 1, 0, ldB) }
        __syncthreads();
    }
#undef P1STEP
#undef C1STEP
}

// ---------------------------------------------------------------------------
// scan2: horizontal recurrence; consumer wave batches 32 output steps in LDS
// and stores 128B/lane (full write granule).
// ---------------------------------------------------------------------------
__global__ __launch_bounds__(128, 2)
void scan2_kernel(const float* __restrict__ A2,  // ws
                  float* __restrict__ out,
                  const float* __restrict__ W5)
{
    __shared__ float vs[2][C64];
    __shared__ float xs[8][C64];
    __shared__ float ob[32][C64];  // 32-step output batch

    const int t   = threadIdx.x;
    const int wid = t >> 6;
    const int o   = t & 63;
    const int g   = blockIdx.x;    // (b, hrow)
    const int b   = g / S;
    const int hr  = g - b * S;

    const int abase = ((b * S + hr) * S) * C64 + o;   // A2 + w*C64
    const int outb  = ((b * C64 + o) * S + hr) * S;   // out + w

    v2f wr2[32];
    {
        const float4* P = (const float4*)(W5 + o * C64);
#pragma unroll
        for (int i = 0; i < 16; ++i) {
            float4 u = P[i];
            wr2[2*i+0] = mk2(u.x, u.y);
            wr2[2*i+1] = mk2(u.z, u.w);
        }
#pragma unroll
        for (int i = 0; i < 32; ++i) asm volatile("" : "+v"(wr2[i]));
    }

    float ldA = 0.f, ldB = 0.f;
    if (wid == 0) {
        vs[1][o] = fmaxf(A2[abase], 0.0f);   // v_0 = relu(col 0)
    } else {
#pragma unroll
        for (int r = 1; r <= 7; ++r) xs[r][o] = A2[abase + r * C64];
        ldA = A2[abase + 8 * C64];
        ldB = A2[abase + 9 * C64];
    }
    __syncthreads();

#define P2STEP(H, PAR)                                                        \
    {                                                                         \
        const float4* vq4 = (const float4*)&vs[PAR][0];                       \
        float aterm = xs[(H) & 7][o];                                         \
        MATVEC(sum_, wr2, vq4, aterm)                                         \
        vs[(PAR) ^ 1][o] = fmaxf(sum_, 0.0f);                                 \
    }
#define C2STEP(H, PAR, LD)                                                    \
    {                                                                         \
        ob[((H) - 1) & 31][o] = vs[PAR][o];                                   \
        xs[((H) + 7) & 7][o] = LD;                                            \
        int hn = (H) + 9; hn = (hn > S - 1) ? (S - 1) : hn;                   \
        LD = A2[abase + hn * C64];                                            \
    }

    for (int h = 1; h <= S; h += 2) {
        if (wid == 0) { P2STEP(h, 1) } else { C2STEP(h, 1, ldA) }
        __syncthreads();
        if (wid == 0) { P2STEP(h + 1, 0) } else { C2STEP(h + 1, 0, ldB) }
        __syncthreads();
        if (wid == 1 && (((h + 1) & 31) == 0)) {
            const int base = (h + 1) - 32;   // store out rows base..base+31
#pragma unroll
            for (int k2 = 0; k2 < 8; ++k2) {
                float4 qv;
                qv.x = ob[4*k2+0][o]; qv.y = ob[4*k2+1][o];
                qv.z = ob[4*k2+2][o]; qv.w = ob[4*k2+3][o];
                *(float4*)(out + outb + base + 4*k2) = qv;
            }
        }
    }
#undef P2STEP
#undef C2STEP
}

extern "C" void kernel_launch(void* const* d_in, const int* in_sizes, int n_in,
                              void* d_out, int out_size, void* d_ws, size_t ws_size,
                              hipStream_t stream) {
    const float* x  = (const float*)d_in[0];
    const float* W1 = (const float*)d_in[1];
    const float* b1 = (const float*)d_in[2];
    const float* W2 = (const float*)d_in[3];
    const float* b2 = (const float*)d_in[4];
    const float* W4 = (const float*)d_in[5];
    const float* b4 = (const float*)d_in[6];
    const float* W5 = (const float*)d_in[7];
    const float* b5 = (const float*)d_in[8];
    float* out = (float*)d_out;
    float* ws  = (float*)d_ws;     // B*S*S*C floats

    prelin_kernel<<<dim3(S, 6, 4), dim3(C64), 0, stream>>>(x, out, W1, b1, b2);
    scan1_kernel<<<dim3(4 * S), dim3(128), 0, stream>>>(out, ws, W2, W4, b4, b5);
    scan2_kernel<<<dim3(4 * S), dim3(128), 0, stream>>>(ws, out, W5);
}